// Round 3
// baseline (5979.262 us; speedup 1.0000x reference)
//
#include <hip/hip_runtime.h>
#include <math.h>

constexpr int TS = 4;     // samples per block
constexpr int NT = 256;   // threads per block
constexpr int H0 = 768;   // HID0 dim per sample
constexpr int H1 = 1536;  // HID1 dim per sample

// ============================================================================
// Clebsch-Gordan init: element-parallel, fp64, registers only.
// offsets: 0:(0,0,0)@0 1:(0,1,1)@1 2:(1,0,1)@10 3:(0,2,2)@19 4:(2,0,2)@44
// 5:(1,1,0)@69 6:(1,1,1)@78 7:(1,1,2)@105 8:(2,1,2)@150 9:(1,2,2)@225
// 10:(2,2,0)@300 11:(2,2,1)@325 12:(2,2,2)@400 ; total 525 floats
// ============================================================================
__device__ inline double dfact(int n){ double r=1.0; for(int i=2;i<=n;i++) r*=(double)i; return r; }

struct dcplx { double x, y; };
__device__ inline dcplx cmul(dcplx a, dcplx b){ return {a.x*b.x-a.y*b.y, a.x*b.y+a.y*b.x}; }

__device__ dcplx Uent(int l, int r, int c){
  double re=0.0, im=0.0;
  double s = 1.0/sqrt(2.0);
  if (r==l && c==l) re = 1.0;
  else if (c>l){ int m=c-l; double sgn=(m&1)?-1.0:1.0;
    if (r==l-m) re = s; else if (r==l+m) re = sgn*s;
  } else if (c<l){ int m=l-c; double sgn=(m&1)?-1.0:1.0;
    if (r==l-m) im = s; else if (r==l+m) im = -sgn*s;
  }
  int lm=l&3; double pr,pi;
  if(lm==0){pr=1;pi=0;} else if(lm==1){pr=0;pi=-1;} else if(lm==2){pr=-1;pi=0;} else {pr=0;pi=1;}
  return { re*pr-im*pi, re*pi+im*pr };
}

__device__ double cg_complex_entry(int l1,int l2,int l3,int m1,int m2){
  int m3=m1+m2;
  if (m3<-l3 || m3>l3) return 0.0;
  double pref = sqrt((double)(2*l3+1)*dfact(l3+l1-l2)*dfact(l3-l1+l2)*dfact(l1+l2-l3)/dfact(l1+l2+l3+1));
  pref *= sqrt(dfact(l3+m3)*dfact(l3-m3)*dfact(l1-m1)*dfact(l1+m1)*dfact(l2-m2)*dfact(l2+m2));
  double s=0.0;
  for(int k=0;k<=l1+l2-l3;k++){
    int a2=l1-m1-k, a3=l2+m2-k, a4=l3-l2+m1+k, a5=l3-l1-m2+k;
    if(a2<0||a3<0||a4<0||a5<0) continue;
    double t=1.0/(dfact(k)*dfact(l1+l2-l3-k)*dfact(a2)*dfact(a3)*dfact(a4)*dfact(a5));
    s += (k&1)? -t : t;
  }
  return pref*s;
}

__global__ void cg_init_kernel(float* cg){
  __shared__ double sKr[525], sKi[525];
  __shared__ double sScale[13];
  __shared__ int    sSel[13];
  const int L1[13]={0,0,1,0,2,1,1,1,2,1,2,2,2};
  const int L2[13]={0,1,0,2,0,1,1,1,1,2,2,2,2};
  const int L3[13]={0,1,1,2,2,0,1,2,2,2,0,1,2};
  const int OFF[14]={0,1,10,19,44,69,78,105,150,225,300,325,400,525};
  const int tid = threadIdx.x;
  int combo=-1, l1=0,l2=0,l3=0;
  if (tid < 525){
    combo=12;
    for(int i=0;i<12;i++) if (tid < OFF[i+1]) { combo=i; break; }
    l1=L1[combo]; l2=L2[combo]; l3=L3[combo];
    int d2=2*l2+1, d3=2*l3+1;
    int e = tid - OFF[combo];
    int a = e/(d2*d3), b=(e/d3)%d2, cc=e%d3;
    double kr=0.0, ki=0.0;
    for(int m=0;m<2*l1+1;m++) for(int n=0;n<d2;n++){
      int m3 = (m-l1)+(n-l2);
      if (m3<-l3||m3>l3) continue;
      double cv = cg_complex_entry(l1,l2,l3,m-l1,n-l2);
      if (cv==0.0) continue;
      dcplx u1=Uent(l1,m,a), u2=Uent(l2,n,b), u3=Uent(l3,m3+l3,cc);
      u3.y = -u3.y;  // conj
      dcplx t = cmul(cmul(u1,u2),u3);
      kr += t.x*cv; ki += t.y*cv;
    }
    sKr[tid]=kr; sKi[tid]=ki;
  }
  __syncthreads();
  if (tid < 13){
    int sz = OFF[tid+1]-OFF[tid];
    double nr=0,ni=0;
    for(int i=0;i<sz;i++){ double r=sKr[OFF[tid]+i], im=sKi[OFF[tid]+i]; nr+=r*r; ni+=im*im; }
    int sel = (nr>=ni)? 0 : 1;
    sSel[tid]=sel;
    sScale[tid] = sqrt((double)(2*L3[tid]+1))/sqrt(sel? ni : nr);
  }
  __syncthreads();
  if (tid < 525){
    double v = sSel[combo]? sKi[tid] : sKr[tid];
    cg[tid] = (float)(v*sScale[combo]);
  }
}

// ============================================================================
// Main fused kernel
// HID0 per-sample layout (768): l0@0(64), l1@64(64x3), l2@256(64x5), l1b@576(64x3)
// HID1 per-sample layout (1536): l0@0(128), l1@128(128x3), l2@512(128x5), l1b@1152
// ============================================================================

__device__ void lin_h(const float* __restrict__ W0, const float* __restrict__ W1,
                      const float* __restrict__ W2, const float* __restrict__ b0,
                      const float* src, float* dst, int tid)
{
  const float rs128 = 0.08838834764831845f; // 1/sqrt(128)
  // l=0: thread = (n,u)
  {
    int u=tid&63, n=tid>>6;
    const float* s=src+n*H0;
    float acc=0.f;
    #pragma unroll 4
    for (int v=0;v<64;v++) acc += s[v]*W0[v*64+u];
    dst[n*H0+u] = acc*0.125f + b0[u];
  }
  // l=1: thread = (j,u), all 4 samples
  for (int it=tid; it<384; it+=NT){
    int u=it&127, j=it>>7;
    float a0=0.f,a1=0.f,a2=0.f,a3=0.f;
    #pragma unroll 4
    for (int v=0;v<64;v++){
      float w=W1[v*128+u];
      int so=64+v*3+j;
      a0+=w*src[so]; a1+=w*src[H0+so]; a2+=w*src[2*H0+so]; a3+=w*src[3*H0+so];
    }
    #pragma unroll 4
    for (int v=0;v<64;v++){
      float w=W1[(v+64)*128+u];
      int so=576+v*3+j;
      a0+=w*src[so]; a1+=w*src[H0+so]; a2+=w*src[2*H0+so]; a3+=w*src[3*H0+so];
    }
    int du=(u<64)?(64+u*3+j):(576+(u-64)*3+j);
    dst[du]=a0*rs128; dst[H0+du]=a1*rs128; dst[2*H0+du]=a2*rs128; dst[3*H0+du]=a3*rs128;
  }
  // l=2: thread = (j,u), all 4 samples
  for (int it=tid; it<320; it+=NT){
    int u=it&63, j=it>>6;
    float a0=0.f,a1=0.f,a2=0.f,a3=0.f;
    #pragma unroll 4
    for (int v=0;v<64;v++){
      float w=W2[v*64+u];
      int so=256+v*5+j;
      a0+=w*src[so]; a1+=w*src[H0+so]; a2+=w*src[2*H0+so]; a3+=w*src[3*H0+so];
    }
    int du=256+u*5+j;
    dst[du]=a0*0.125f; dst[H0+du]=a1*0.125f; dst[2*H0+du]=a2*0.125f; dst[3*H0+du]=a3*0.125f;
  }
}

// stage 64x64 w transposed into s_w[v*65+u]  (writes: 2-way bank alias = free)
__device__ __forceinline__ void stage_w(const float* __restrict__ wp, float* s_w, int tid){
  const float4* wp4 = (const float4*)wp;
  #pragma unroll
  for (int t=0;t<4;t++){
    int i = t*NT + tid;          // float4 index in [0,1024)
    float4 w4 = wp4[i];
    int u = i>>4;
    int v0 = (i&15)*4;
    s_w[(v0  )*65+u] = w4.x;
    s_w[(v0+1)*65+u] = w4.y;
    s_w[(v0+2)*65+u] = w4.z;
    s_w[(v0+3)*65+u] = w4.w;
  }
}

// one uvu/fc path's per-(n,u) contribution, accumulated into caller's tk[D3].
// Short live range: bacc/x1v die at return; tk lives only within a small group.
template<int D1,int D2,int D3,int O1,int O2,int CGO>
__device__ __forceinline__ void path_acc(const float* __restrict__ wp,
    const float* s1, const float* s2, float* s_w, const float* s_cg,
    float* tk, int tid)
{
  __syncthreads();               // prior readers of s_w done
  stage_w(wp, s_w, tid);
  __syncthreads();
  int u = tid & 63, n = tid >> 6;
  float bacc[D2];
  #pragma unroll
  for (int j=0;j<D2;j++) bacc[j]=0.f;
  const float* x2p = s2 + n*H0 + O2;
  #pragma unroll 4
  for (int v=0;v<64;v++){
    float wv = s_w[v*65+u];
    #pragma unroll
    for (int j=0;j<D2;j++) bacc[j] += wv * x2p[v*D2+j];
  }
  float x1v[D1];
  #pragma unroll
  for (int i=0;i<D1;i++) x1v[i] = s1[n*H0 + O1 + u*D1 + i];
  #pragma unroll
  for (int i=0;i<D1;i++){
    #pragma unroll
    for (int j=0;j<D2;j++){
      float pr = x1v[i]*bacc[j];
      #pragma unroll
      for (int k=0;k<D3;k++) tk[k] += pr*s_cg[CGO+(i*D2+j)*D3+k];
    }
  }
}

// paths grouped by output segment => tiny accumulators, one LDS write per group
__device__ void tp_uvu_all(const float* tw, const float* s1, const float* s2, float* dst,
                           float* s_w, const float* s_cg, int tid)
{
  const float f192 = 0.07216878364870323f;  // 1/sqrt(192)
  const float f256 = 0.0625f;               // 1/sqrt(256)
  int u=tid&63, n=tid>>6;
  float* dp = dst + n*H0;
  { // out l0 @0, fan 192: paths 0,5,10
    float tk[1]={0.f};
    path_acc<1,1,1,  0,  0,  0>(tw+ 0*4096, s1,s2,s_w,s_cg,tk,tid);
    path_acc<3,3,1, 64, 64, 69>(tw+ 5*4096, s1,s2,s_w,s_cg,tk,tid);
    path_acc<5,5,1,256,256,300>(tw+10*4096, s1,s2,s_w,s_cg,tk,tid);
    dp[u] = tk[0]*f192;
  }
  { // out l1 @64, fan 256: paths 1,4,6,11
    float tk[3]={0.f,0.f,0.f};
    path_acc<1,3,3,  0, 64,  1>(tw+ 1*4096, s1,s2,s_w,s_cg,tk,tid);
    path_acc<3,1,3, 64,  0, 10>(tw+ 4*4096, s1,s2,s_w,s_cg,tk,tid);
    path_acc<3,3,3, 64, 64, 78>(tw+ 6*4096, s1,s2,s_w,s_cg,tk,tid);
    path_acc<5,5,3,256,256,325>(tw+11*4096, s1,s2,s_w,s_cg,tk,tid);
    #pragma unroll
    for (int k=0;k<3;k++) dp[64+u*3+k] = tk[k]*f256;
  }
  { // out l2 @256, fan 256: paths 2,8,9,13
    float tk[5]={0.f,0.f,0.f,0.f,0.f};
    path_acc<1,5,5,  0,256, 19>(tw+ 2*4096, s1,s2,s_w,s_cg,tk,tid);
    path_acc<5,1,5,256,  0, 44>(tw+ 8*4096, s1,s2,s_w,s_cg,tk,tid);
    path_acc<5,3,5,256, 64,150>(tw+ 9*4096, s1,s2,s_w,s_cg,tk,tid);
    path_acc<5,3,5,256,576,150>(tw+13*4096, s1,s2,s_w,s_cg,tk,tid);
    #pragma unroll
    for (int k=0;k<5;k++) dp[256+u*5+k] = tk[k]*f256;
  }
  { // out l1b @576, fan 192: paths 3,7,12
    float tk[3]={0.f,0.f,0.f};
    path_acc<1,3,3,  0,576,  1>(tw+ 3*4096, s1,s2,s_w,s_cg,tk,tid);
    path_acc<3,3,3, 64, 64, 78>(tw+ 7*4096, s1,s2,s_w,s_cg,tk,tid);
    path_acc<5,5,3,256,256,325>(tw+12*4096, s1,s2,s_w,s_cg,tk,tid);
    #pragma unroll
    for (int k=0;k<3;k++) dp[576+u*3+k] = tk[k]*f192;
  }
}

// wave-wide reduce of tk[D3] over u, write to s_out (single writer per slot)
template<int D3>
__device__ __forceinline__ void wave_reduce_out(float* tk, float* s_out, int n, int u, int iob){
  #pragma unroll
  for (int k=0;k<D3;k++){
    float v = tk[k];
    v += __shfl_down(v, 32, 64);
    v += __shfl_down(v, 16, 64);
    v += __shfl_down(v,  8, 64);
    v += __shfl_down(v,  4, 64);
    v += __shfl_down(v,  2, 64);
    v += __shfl_down(v,  1, 64);
    if (u==0) s_out[n*6 + iob + k] = v;
  }
}

__global__ __launch_bounds__(NT, 2) void deeprst_main(
    const float* __restrict__ x,
    const float* __restrict__ l1W0, const float* __restrict__ l1W1,
    const float* __restrict__ l1W2, const float* __restrict__ l1b0,
    const float* __restrict__ l2W0, const float* __restrict__ l2W1,
    const float* __restrict__ l2W2, const float* __restrict__ l2b0,
    const float* __restrict__ LW0, const float* __restrict__ LW1,
    const float* __restrict__ LW2, const float* __restrict__ Lb0,
    const float* __restrict__ tpw, const float* __restrict__ tp4w,
    const float* __restrict__ cg, float* __restrict__ out)
{
  __shared__ float sA[3*TS*H0];   // 9216 floats: 3 rotating state buffers
  __shared__ float s_w[64*65];    // transposed padded path-weight tile
  __shared__ float s_cg[525];
  __shared__ float s_out[TS*6];

  const int tid = threadIdx.x;
  const int n0 = blockIdx.x * TS;
  const float rs128 = 0.08838834764831845f;
  const float rs8   = 0.3535533905932738f;

  for (int i=tid;i<525;i+=NT) s_cg[i]=cg[i];

  float* h1 = sA;              // TS*1536 floats (buffers 0+1)
  float* B2 = sA + 2*TS*H0;

  // ---- lin1: x (80) -> h1 (HID1) ----
  for (int idx=tid; idx<TS*128; idx+=NT){
    int u=idx&127, n=idx>>7;
    const float* xp = x + (n0+n)*80;
    float acc=0.f;
    #pragma unroll
    for (int v=0;v<16;v++) acc += xp[v]*l1W0[v*128+u];
    h1[n*H1+u] = acc*0.25f + l1b0[u];
  }
  for (int idx=tid; idx<TS*768; idx+=NT){
    int u=idx&255, j=(idx>>8)%3, n=idx/768;
    const float* xp = x + (n0+n)*80 + 16;
    float acc=0.f;
    #pragma unroll
    for (int v=0;v<8;v++) acc += xp[v*3+j]*l1W1[v*256+u];
    int du = (u<128)? (128+u*3+j) : (1152+(u-128)*3+j);
    h1[n*H1+du] = acc*rs8;
  }
  for (int idx=tid; idx<TS*640; idx+=NT){
    int u=idx&127, j=(idx>>7)%5, n=idx/640;
    const float* xp = x + (n0+n)*80 + 40;
    float acc=0.f;
    #pragma unroll
    for (int v=0;v<8;v++) acc += xp[v*5+j]*l1W2[v*128+u];
    h1[n*H1+512+u*5+j] = acc*rs8;
  }
  __syncthreads();

  // ---- lin2: h1 (HID1) -> B2 (HID0) ----
  {
    int u=tid&63, n=tid>>6;
    const float* s=h1+n*H1;
    float acc=0.f;
    #pragma unroll 4
    for (int v=0;v<128;v++) acc += s[v]*l2W0[v*64+u];
    B2[n*H0+u] = acc*rs128 + l2b0[u];
  }
  for (int it=tid; it<384; it+=NT){
    int u=it&127, j=it>>7;
    float a0=0.f,a1=0.f,a2=0.f,a3=0.f;
    #pragma unroll 4
    for (int v=0;v<128;v++){
      float w=l2W1[v*128+u];
      int so=128+v*3+j;
      a0+=w*h1[so]; a1+=w*h1[H1+so]; a2+=w*h1[2*H1+so]; a3+=w*h1[3*H1+so];
    }
    #pragma unroll 4
    for (int v=0;v<128;v++){
      float w=l2W1[(v+128)*128+u];
      int so=1152+v*3+j;
      a0+=w*h1[so]; a1+=w*h1[H1+so]; a2+=w*h1[2*H1+so]; a3+=w*h1[3*H1+so];
    }
    int du=(u<64)?(64+u*3+j):(576+(u-64)*3+j);
    B2[du]=a0*0.0625f; B2[H0+du]=a1*0.0625f; B2[2*H0+du]=a2*0.0625f; B2[3*H0+du]=a3*0.0625f;
  }
  for (int it=tid; it<320; it+=NT){
    int u=it&63, j=it>>6;
    float a0=0.f,a1=0.f,a2=0.f,a3=0.f;
    #pragma unroll 4
    for (int v=0;v<128;v++){
      float w=l2W2[v*64+u];
      int so=512+v*5+j;
      a0+=w*h1[so]; a1+=w*h1[H1+so]; a2+=w*h1[2*H1+so]; a3+=w*h1[3*H1+so];
    }
    int du=256+u*5+j;
    B2[du]=a0*rs128; B2[H0+du]=a1*rs128; B2[2*H0+du]=a2*rs128; B2[3*H0+du]=a3*rs128;
  }
  __syncthreads();

  // ---- 3 rounds: split -> tp_uvu -> linear ----
  float* h  = B2;
  float* u0 = sA;
  float* u1 = sA + TS*H0;
  for (int r=0;r<3;r++){
    lin_h(LW0+(3*r  )*4096, LW1+(3*r  )*16384, LW2+(3*r  )*4096, Lb0+(3*r  )*64, h, u0, tid);
    lin_h(LW0+(3*r+1)*4096, LW1+(3*r+1)*16384, LW2+(3*r+1)*4096, Lb0+(3*r+1)*64, h, u1, tid);
    __syncthreads();
    tp_uvu_all(tpw + r*14*4096, u0, u1, h, s_w, s_cg, tid); // ht overwrites h
    __syncthreads();
    lin_h(LW0+(3*r+2)*4096, LW1+(3*r+2)*16384, LW2+(3*r+2)*4096, Lb0+(3*r+2)*64, h, u0, tid);
    __syncthreads();
    float* nh=u0; u0=u1; u1=h; h=nh;
  }

  // ---- split4 + fully-connected TP (paths grouped by output) ----
  lin_h(LW0+ 9*4096, LW1+ 9*16384, LW2+ 9*4096, Lb0+ 9*64, h, u0, tid);
  lin_h(LW0+10*4096, LW1+10*16384, LW2+10*4096, Lb0+10*64, h, u1, tid);
  __syncthreads();

  {
    int u=tid&63, n=tid>>6;
    { // out 0e (slot 0): fc paths 0..5
      float tk[1]={0.f};
      path_acc<1,1,1,  0,  0,  0>(tp4w+ 0*4096, u0,u1,s_w,s_cg,tk,tid);
      path_acc<3,3,1, 64, 64, 69>(tp4w+ 1*4096, u0,u1,s_w,s_cg,tk,tid);
      path_acc<3,3,1, 64,576, 69>(tp4w+ 2*4096, u0,u1,s_w,s_cg,tk,tid);
      path_acc<5,5,1,256,256,300>(tp4w+ 3*4096, u0,u1,s_w,s_cg,tk,tid);
      path_acc<3,3,1,576, 64, 69>(tp4w+ 4*4096, u0,u1,s_w,s_cg,tk,tid);
      path_acc<3,3,1,576,576, 69>(tp4w+ 5*4096, u0,u1,s_w,s_cg,tk,tid);
      wave_reduce_out<1>(tk, s_out, n, u, 0);
    }
    { // out 2e (slots 1..5): fc paths 6..16
      float tk[5]={0.f,0.f,0.f,0.f,0.f};
      path_acc<1,5,5,  0,256, 19>(tp4w+ 6*4096, u0,u1,s_w,s_cg,tk,tid);
      path_acc<3,3,5, 64, 64,105>(tp4w+ 7*4096, u0,u1,s_w,s_cg,tk,tid);
      path_acc<3,5,5, 64,256,225>(tp4w+ 8*4096, u0,u1,s_w,s_cg,tk,tid);
      path_acc<3,3,5, 64,576,105>(tp4w+ 9*4096, u0,u1,s_w,s_cg,tk,tid);
      path_acc<5,1,5,256,  0, 44>(tp4w+10*4096, u0,u1,s_w,s_cg,tk,tid);
      path_acc<5,3,5,256, 64,150>(tp4w+11*4096, u0,u1,s_w,s_cg,tk,tid);
      path_acc<5,5,5,256,256,400>(tp4w+12*4096, u0,u1,s_w,s_cg,tk,tid);
      path_acc<5,3,5,256,576,150>(tp4w+13*4096, u0,u1,s_w,s_cg,tk,tid);
      path_acc<3,3,5,576, 64,105>(tp4w+14*4096, u0,u1,s_w,s_cg,tk,tid);
      path_acc<3,5,5,576,256,225>(tp4w+15*4096, u0,u1,s_w,s_cg,tk,tid);
      path_acc<3,3,5,576,576,105>(tp4w+16*4096, u0,u1,s_w,s_cg,tk,tid);
      wave_reduce_out<5>(tk, s_out, n, u, 1);
    }
  }
  __syncthreads();

  if (tid < TS*6){
    int n=tid/6, k=tid%6;
    float sc = (k==0)? (1.0f/sqrtf(24576.0f)) : (1.0f/sqrtf(45056.0f));
    out[(n0+n)*6+k] = s_out[tid]*sc;
  }
}

// ============================================================================
extern "C" void kernel_launch(void* const* d_in, const int* in_sizes, int n_in,
                              void* d_out, int out_size, void* d_ws, size_t ws_size,
                              hipStream_t stream)
{
  (void)n_in; (void)out_size; (void)ws_size;
  const float* x    = (const float*)d_in[0];
  const float* l1W0 = (const float*)d_in[1];
  const float* l1W1 = (const float*)d_in[2];
  const float* l1W2 = (const float*)d_in[3];
  const float* l1b0 = (const float*)d_in[4];
  const float* l2W0 = (const float*)d_in[5];
  const float* l2W1 = (const float*)d_in[6];
  const float* l2W2 = (const float*)d_in[7];
  const float* l2b0 = (const float*)d_in[8];
  const float* LW0  = (const float*)d_in[9];
  const float* LW1  = (const float*)d_in[10];
  const float* LW2  = (const float*)d_in[11];
  const float* Lb0  = (const float*)d_in[12];
  const float* tpw  = (const float*)d_in[13];
  const float* tp4w = (const float*)d_in[14];
  float* cg = (float*)d_ws;   // 525 floats; ws re-poisoned every launch -> recompute
  const int n = in_sizes[0]/80;

  cg_init_kernel<<<1, 576, 0, stream>>>(cg);
  deeprst_main<<<n/TS, NT, 0, stream>>>(x,l1W0,l1W1,l1W2,l1b0,l2W0,l2W1,l2W2,l2b0,
                                        LW0,LW1,LW2,Lb0,tpw,tp4w,cg,(float*)d_out);
}

// Round 5
// 1339.095 us; speedup vs baseline: 4.4652x; 4.4652x over previous
//
#include <hip/hip_runtime.h>
#include <math.h>

constexpr int TS = 16;     // samples per block
constexpr int NT = 512;    // threads per block (8 waves)
constexpr int SSTRIDE = 776;   // bf16 per sample, HID0 state (768 + 8 pad)
constexpr int H1S = 1544;      // bf16 per sample, HID1 transient (1536 + 8 pad)
constexpr int BUF = TS*SSTRIDE;
// HID0 per-sample layout: l0 @0 (64: [u]), l1 @64 (3x64: [i][u]),
// l2 @256 (5x64), l1b @576 (3x64)
// HID1 layout: l0 @0 (128), l1 @128 (3x128), l2 @512 (5x128), l1b @1152 (3x128)

typedef __attribute__((ext_vector_type(8))) short bf16x8;
typedef __attribute__((ext_vector_type(4))) float f32x4;

__device__ inline f32x4 mfma16(bf16x8 a, bf16x8 b, f32x4 c){
  return __builtin_amdgcn_mfma_f32_16x16x32_bf16(a, b, c, 0, 0, 0);
}
__device__ inline unsigned short f2b(float f){
  union { float f; unsigned u; } v; v.f = f;
  return (unsigned short)((v.u + 0x7fffu + ((v.u >> 16) & 1u)) >> 16);
}
__device__ inline float b2f(unsigned short h){
  union { unsigned u; float f; } v; v.u = ((unsigned)h) << 16; return v.f;
}
__device__ inline void store_hl(unsigned short* ph, unsigned short* pl, int idx, float v){
  unsigned short h = f2b(v);
  ph[idx] = h;
  pl[idx] = f2b(v - b2f(h));
}
#define LDFRAG(p) (*(const bf16x8*)(p))

// ws bf16 weight offsets (elements, base = ws+4096B). lo plane at +W_TOT.
constexpr int OFF_L2W0 = 0;        // 64x128 (WT[o][k])
constexpr int OFF_L2W1 = 8192;     // 128x256
constexpr int OFF_L2W2 = 40960;    // 64x128
constexpr int OFF_LW0  = 49152;    // 11 x 64x64
constexpr int OFF_LW1  = 94208;    // 11 x 128x128
constexpr int OFF_LW2  = 274432;   // 11 x 64x64
constexpr int OFF_TPW  = 319488;   // 3x14 x 64x64 ([u][v])
constexpr int OFF_TP4W = 491520;   // 17 x 64x64
constexpr int W_TOT    = 561152;

// ============================================================================
// Clebsch-Gordan init (element-parallel fp64; verified R2/R3)
// offsets: 0:(0,0,0)@0 1:(0,1,1)@1 2:(1,0,1)@10 3:(0,2,2)@19 4:(2,0,2)@44
// 5:(1,1,0)@69 6:(1,1,1)@78 7:(1,1,2)@105 8:(2,1,2)@150 9:(1,2,2)@225
// 10:(2,2,0)@300 11:(2,2,1)@325 12:(2,2,2)@400 ; total 525 floats
// ============================================================================
__device__ inline double dfact(int n){ double r=1.0; for(int i=2;i<=n;i++) r*=(double)i; return r; }
struct dcplx { double x, y; };
__device__ inline dcplx cmul(dcplx a, dcplx b){ return {a.x*b.x-a.y*b.y, a.x*b.y+a.y*b.x}; }

__device__ dcplx Uent(int l, int r, int c){
  double re=0.0, im=0.0;
  double s = 1.0/sqrt(2.0);
  if (r==l && c==l) re = 1.0;
  else if (c>l){ int m=c-l; double sgn=(m&1)?-1.0:1.0;
    if (r==l-m) re = s; else if (r==l+m) re = sgn*s;
  } else if (c<l){ int m=l-c; double sgn=(m&1)?-1.0:1.0;
    if (r==l-m) im = s; else if (r==l+m) im = -sgn*s;
  }
  int lm=l&3; double pr,pi;
  if(lm==0){pr=1;pi=0;} else if(lm==1){pr=0;pi=-1;} else if(lm==2){pr=-1;pi=0;} else {pr=0;pi=1;}
  return { re*pr-im*pi, re*pi+im*pr };
}

__device__ double cg_complex_entry(int l1,int l2,int l3,int m1,int m2){
  int m3=m1+m2;
  if (m3<-l3 || m3>l3) return 0.0;
  double pref = sqrt((double)(2*l3+1)*dfact(l3+l1-l2)*dfact(l3-l1+l2)*dfact(l1+l2-l3)/dfact(l1+l2+l3+1));
  pref *= sqrt(dfact(l3+m3)*dfact(l3-m3)*dfact(l1-m1)*dfact(l1+m1)*dfact(l2-m2)*dfact(l2+m2));
  double s=0.0;
  for(int k=0;k<=l1+l2-l3;k++){
    int a2=l1-m1-k, a3=l2+m2-k, a4=l3-l2+m1+k, a5=l3-l1-m2+k;
    if(a2<0||a3<0||a4<0||a5<0) continue;
    double t=1.0/(dfact(k)*dfact(l1+l2-l3-k)*dfact(a2)*dfact(a3)*dfact(a4)*dfact(a5));
    s += (k&1)? -t : t;
  }
  return pref*s;
}

__global__ void cg_init_kernel(float* cg){
  __shared__ double sKr[525], sKi[525];
  __shared__ double sScale[13];
  __shared__ int    sSel[13];
  const int L1[13]={0,0,1,0,2,1,1,1,2,1,2,2,2};
  const int L2[13]={0,1,0,2,0,1,1,1,1,2,2,2,2};
  const int L3[13]={0,1,1,2,2,0,1,2,2,2,0,1,2};
  const int OFF[14]={0,1,10,19,44,69,78,105,150,225,300,325,400,525};
  const int tid = threadIdx.x;
  int combo=-1, l1=0,l2=0,l3=0;
  if (tid < 525){
    combo=12;
    for(int i=0;i<12;i++) if (tid < OFF[i+1]) { combo=i; break; }
    l1=L1[combo]; l2=L2[combo]; l3=L3[combo];
    int d2=2*l2+1, d3=2*l3+1;
    int e = tid - OFF[combo];
    int a = e/(d2*d3), b=(e/d3)%d2, cc=e%d3;
    double kr=0.0, ki=0.0;
    for(int m=0;m<2*l1+1;m++) for(int n=0;n<d2;n++){
      int m3 = (m-l1)+(n-l2);
      if (m3<-l3||m3>l3) continue;
      double cv = cg_complex_entry(l1,l2,l3,m-l1,n-l2);
      if (cv==0.0) continue;
      dcplx u1=Uent(l1,m,a), u2=Uent(l2,n,b), u3=Uent(l3,m3+l3,cc);
      u3.y = -u3.y;
      dcplx t = cmul(cmul(u1,u2),u3);
      kr += t.x*cv; ki += t.y*cv;
    }
    sKr[tid]=kr; sKi[tid]=ki;
  }
  __syncthreads();
  if (tid < 13){
    int sz = OFF[tid+1]-OFF[tid];
    double nr=0,ni=0;
    for(int i=0;i<sz;i++){ double r=sKr[OFF[tid]+i], im=sKi[OFF[tid]+i]; nr+=r*r; ni+=im*im; }
    int sel = (nr>=ni)? 0 : 1;
    sSel[tid]=sel;
    sScale[tid] = sqrt((double)(2*L3[tid]+1))/sqrt(sel? ni : nr);
  }
  __syncthreads();
  if (tid < 525){
    double v = sSel[combo]? sKi[tid] : sKr[tid];
    cg[tid] = (float)(v*sScale[combo]);
  }
}

// ============================================================================
// Weight prep: fp32 -> bf16 hi/lo planes. Linear weights transposed WT[o][k];
// TP weights [u][v].
// ============================================================================
__global__ void prep_kernel(const float* __restrict__ l2W0, const float* __restrict__ l2W1,
                            const float* __restrict__ l2W2, const float* __restrict__ LW0,
                            const float* __restrict__ LW1, const float* __restrict__ LW2,
                            const float* __restrict__ tpw, const float* __restrict__ tp4w,
                            unsigned short* __restrict__ wb){
  int i = blockIdx.x*256 + threadIdx.x;
  if (i >= W_TOT) return;
  float v;
  if (i < 8192){ int o=i>>7, k=i&127; v = l2W0[k*64+o]; }
  else if (i < 40960){ int j=i-8192; int o=j>>8, k=j&255; v = l2W1[k*128+o]; }
  else if (i < 49152){ int j=i-40960; int o=j>>7, k=j&127; v = l2W2[k*64+o]; }
  else if (i < 94208){ int j=i-49152; int li=j>>12, r=j&4095, o=r>>6, k=r&63; v = LW0[li*4096+k*64+o]; }
  else if (i < 274432){ int j=i-94208; int li=j>>14, r=j&16383, o=r>>7, k=r&127; v = LW1[li*16384+k*128+o]; }
  else if (i < 319488){ int j=i-274432; int li=j>>12, r=j&4095, o=r>>6, k=r&63; v = LW2[li*4096+k*64+o]; }
  else if (i < 491520){ v = tpw[i-319488]; }
  else { v = tp4w[i-491520]; }
  unsigned short h = f2b(v);
  wb[i] = h;
  wb[W_TOT + i] = f2b(v - b2f(h));
}

// ============================================================================
// MFMA linear HID0->HID0 (hi/lo). Jobs: 0..3 l0 | 4..11 l1 | 12..15 l2.
// ============================================================================
__device__ void linL_mfma(const unsigned short* __restrict__ wb, int o0, int o1, int o2,
                          const float* __restrict__ b0,
                          const unsigned short* sh, const unsigned short* sl,
                          unsigned short* dh, unsigned short* dl, int wave, int lane)
{
  const float rs128 = 0.08838834764831845f;
  int l16 = lane & 15, quad = lane >> 4;
  int abase = l16 * SSTRIDE;
  for (int job = wave; job < 16; job += 8){
    if (job < 4){                 // l0: K=64, /8 + bias
      int col = job*16 + l16;
      f32x4 a0 = {0,0,0,0}, a1 = {0,0,0,0};
      #pragma unroll
      for (int ks=0; ks<2; ks++){
        int so = abase + ks*32 + quad*8;
        bf16x8 xh = LDFRAG(sh+so), xl = LDFRAG(sl+so);
        int wo = o0 + col*64 + ks*32 + quad*8;
        bf16x8 wh = LDFRAG(wb+wo), wl = LDFRAG(wb+W_TOT+wo);
        a0 = mfma16(xh,wh,a0); a1 = mfma16(xh,wl,a1); a1 = mfma16(xl,wh,a1);
      }
      float bias = b0[col];
      #pragma unroll
      for (int r=0;r<4;r++)
        store_hl(dh,dl,(quad*4+r)*SSTRIDE + col, (a0[r]+a1[r])*0.125f + bias);
    } else if (job < 12){         // l1: K=128 (l1|l1b), /sqrt(128)
      int nt = job-4; int col = nt*16 + l16;
      #pragma unroll
      for (int i=0;i<3;i++){
        f32x4 a0 = {0,0,0,0}, a1 = {0,0,0,0};
        #pragma unroll
        for (int ks=0; ks<4; ks++){
          int ka = ks*32 + quad*8;
          int so = abase + ((ka < 64) ? (64 + i*64 + ka) : (576 + i*64 + ka - 64));
          bf16x8 xh = LDFRAG(sh+so), xl = LDFRAG(sl+so);
          int wo = o1 + col*128 + ka;
          bf16x8 wh = LDFRAG(wb+wo), wl = LDFRAG(wb+W_TOT+wo);
          a0 = mfma16(xh,wh,a0); a1 = mfma16(xh,wl,a1); a1 = mfma16(xl,wh,a1);
        }
        int dof = (col < 64) ? (64 + i*64 + col) : (576 + i*64 + col - 64);
        #pragma unroll
        for (int r=0;r<4;r++)
          store_hl(dh,dl,(quad*4+r)*SSTRIDE + dof, (a0[r]+a1[r])*rs128);
      }
    } else {                      // l2: K=64, /8
      int nt = job-12; int col = nt*16 + l16;
      #pragma unroll
      for (int i=0;i<5;i++){
        f32x4 a0 = {0,0,0,0}, a1 = {0,0,0,0};
        #pragma unroll
        for (int ks=0; ks<2; ks++){
          int so = abase + 256 + i*64 + ks*32 + quad*8;
          bf16x8 xh = LDFRAG(sh+so), xl = LDFRAG(sl+so);
          int wo = o2 + col*64 + ks*32 + quad*8;
          bf16x8 wh = LDFRAG(wb+wo), wl = LDFRAG(wb+W_TOT+wo);
          a0 = mfma16(xh,wh,a0); a1 = mfma16(xh,wl,a1); a1 = mfma16(xl,wh,a1);
        }
        #pragma unroll
        for (int r=0;r<4;r++)
          store_hl(dh,dl,(quad*4+r)*SSTRIDE + 256 + i*64 + col, (a0[r]+a1[r])*0.125f);
      }
    }
  }
}

// lin2: HID1 -> HID0 (K=128/256/128), hi/lo
__device__ void lin2_mfma(const unsigned short* __restrict__ wb,
                          const float* __restrict__ b0,
                          const unsigned short* h1h, const unsigned short* h1l,
                          unsigned short* dh, unsigned short* dl, int wave, int lane)
{
  const float rs128 = 0.08838834764831845f;
  int l16 = lane & 15, quad = lane >> 4;
  int abase = l16 * H1S;
  for (int job = wave; job < 16; job += 8){
    if (job < 4){                 // l0: K=128
      int col = job*16 + l16;
      f32x4 a0 = {0,0,0,0}, a1 = {0,0,0,0};
      #pragma unroll
      for (int ks=0; ks<4; ks++){
        int so = abase + ks*32 + quad*8;
        bf16x8 xh = LDFRAG(h1h+so), xl = LDFRAG(h1l+so);
        int wo = OFF_L2W0 + col*128 + ks*32 + quad*8;
        bf16x8 wh = LDFRAG(wb+wo), wl = LDFRAG(wb+W_TOT+wo);
        a0 = mfma16(xh,wh,a0); a1 = mfma16(xh,wl,a1); a1 = mfma16(xl,wh,a1);
      }
      float bias = b0[col];
      #pragma unroll
      for (int r=0;r<4;r++)
        store_hl(dh,dl,(quad*4+r)*SSTRIDE + col, (a0[r]+a1[r])*rs128 + bias);
    } else if (job < 12){         // l1: K=256, /16
      int nt = job-4; int col = nt*16 + l16;
      #pragma unroll
      for (int i=0;i<3;i++){
        f32x4 a0 = {0,0,0,0}, a1 = {0,0,0,0};
        #pragma unroll
        for (int ks=0; ks<8; ks++){
          int ka = ks*32 + quad*8;
          int so = abase + ((ka < 128) ? (128 + i*128 + ka) : (1152 + i*128 + ka - 128));
          bf16x8 xh = LDFRAG(h1h+so), xl = LDFRAG(h1l+so);
          int wo = OFF_L2W1 + col*256 + ka;
          bf16x8 wh = LDFRAG(wb+wo), wl = LDFRAG(wb+W_TOT+wo);
          a0 = mfma16(xh,wh,a0); a1 = mfma16(xh,wl,a1); a1 = mfma16(xl,wh,a1);
        }
        int dof = (col < 64) ? (64 + i*64 + col) : (576 + i*64 + col - 64);
        #pragma unroll
        for (int r=0;r<4;r++)
          store_hl(dh,dl,(quad*4+r)*SSTRIDE + dof, (a0[r]+a1[r])*0.0625f);
      }
    } else {                      // l2: K=128
      int nt = job-12; int col = nt*16 + l16;
      #pragma unroll
      for (int i=0;i<5;i++){
        f32x4 a0 = {0,0,0,0}, a1 = {0,0,0,0};
        #pragma unroll
        for (int ks=0; ks<4; ks++){
          int so = abase + 512 + i*128 + ks*32 + quad*8;
          bf16x8 xh = LDFRAG(h1h+so), xl = LDFRAG(h1l+so);
          int wo = OFF_L2W2 + col*128 + ks*32 + quad*8;
          bf16x8 wh = LDFRAG(wb+wo), wl = LDFRAG(wb+W_TOT+wo);
          a0 = mfma16(xh,wh,a0); a1 = mfma16(xh,wl,a1); a1 = mfma16(xl,wh,a1);
        }
        #pragma unroll
        for (int r=0;r<4;r++)
          store_hl(dh,dl,(quad*4+r)*SSTRIDE + 256 + i*64 + col, (a0[r]+a1[r])*rs128);
      }
    }
  }
}

// ============================================================================
// TP path, chunked: stage b for JC (<=3) j-columns via 3-MFMA hi/lo, then
// scalar CG partial contraction. CG coeffs read from global (uniform s_load).
// ============================================================================
template<int D1,int D2,int D3,int JC,int J0,int O1,int O2,int CGO>
__device__ __forceinline__ void tp_chunk(
    const unsigned short* __restrict__ wb, int wo,
    const unsigned short* s1h, const unsigned short* s1l,
    const unsigned short* s2h, const unsigned short* s2l,
    float* b_s, const float* __restrict__ cgp,
    float* tk0, float* tk1, int wave, int lane)
{
  __syncthreads();               // prior b_s readers / state writers done
  {
    int l16 = lane & 15, quad = lane >> 4;
    for (int job = wave; job < 4*JC; job += 8){
      int mt = job & 3, jj = job >> 2;
      int j = J0 + jj;
      f32x4 a0 = {0,0,0,0}, a1 = {0,0,0,0};
      #pragma unroll
      for (int ks=0; ks<2; ks++){
        int wofs = wo + (mt*16 + l16)*64 + ks*32 + quad*8;
        bf16x8 wh = LDFRAG(wb + wofs);
        bf16x8 wl = LDFRAG(wb + W_TOT + wofs);
        int sofs = l16*SSTRIDE + O2 + j*64 + ks*32 + quad*8;
        bf16x8 xh = LDFRAG(s2h + sofs);
        bf16x8 xl = LDFRAG(s2l + sofs);
        a0 = mfma16(wh,xh,a0); a1 = mfma16(wh,xl,a1); a1 = mfma16(wl,xh,a1);
      }
      #pragma unroll
      for (int r=0;r<4;r++) a0[r] += a1[r];
      *(f32x4*)&b_s[(jj*16 + l16)*68 + mt*16 + quad*4] = a0;
    }
  }
  __syncthreads();
  #pragma unroll
  for (int p=0;p<2;p++){
    int n = wave + 8*p, u = lane;
    float* tk = p ? tk1 : tk0;
    float x1v[D1], bv[JC];
    #pragma unroll
    for (int i=0;i<D1;i++){
      int o = n*SSTRIDE + O1 + i*64 + u;
      x1v[i] = b2f(s1h[o]) + b2f(s1l[o]);
    }
    #pragma unroll
    for (int jj=0;jj<JC;jj++) bv[jj] = b_s[(jj*16 + n)*68 + u];
    #pragma unroll
    for (int i=0;i<D1;i++){
      #pragma unroll
      for (int jj=0;jj<JC;jj++){
        float pr = x1v[i]*bv[jj];
        #pragma unroll
        for (int k=0;k<D3;k++) tk[k] += pr*cgp[CGO + (i*D2 + J0+jj)*D3 + k];
      }
    }
  }
}

template<int D1,int D2,int D3,int O1,int O2,int CGO>
__device__ __forceinline__ void tp_path(
    const unsigned short* __restrict__ wb, int wo,
    const unsigned short* s1h, const unsigned short* s1l,
    const unsigned short* s2h, const unsigned short* s2l,
    float* b_s, const float* __restrict__ cgp,
    float* tk0, float* tk1, int wave, int lane)
{
  if constexpr (D2 <= 3){
    tp_chunk<D1,D2,D3,D2,0,O1,O2,CGO>(wb,wo,s1h,s1l,s2h,s2l,b_s,cgp,tk0,tk1,wave,lane);
  } else {
    tp_chunk<D1,D2,D3,3,0,O1,O2,CGO>(wb,wo,s1h,s1l,s2h,s2l,b_s,cgp,tk0,tk1,wave,lane);
    tp_chunk<D1,D2,D3,2,3,O1,O2,CGO>(wb,wo,s1h,s1l,s2h,s2l,b_s,cgp,tk0,tk1,wave,lane);
  }
}

__device__ void tp_uvu_all(const unsigned short* __restrict__ wb, int two,
    const unsigned short* s1h, const unsigned short* s1l,
    const unsigned short* s2h, const unsigned short* s2l,
    unsigned short* dh, unsigned short* dl,
    float* b_s, const float* __restrict__ cgp, int wave, int lane)
{
  const float f192 = 0.07216878364870323f;  // 1/sqrt(192)
  const float f256 = 0.0625f;               // 1/sqrt(256)
  { // out l0 @0 (fan 192): paths 0,5,10
    float tk0[1]={0.f}, tk1[1]={0.f};
    tp_path<1,1,1,  0,  0,  0>(wb,two+ 0*4096, s1h,s1l,s2h,s2l,b_s,cgp,tk0,tk1,wave,lane);
    tp_path<3,3,1, 64, 64, 69>(wb,two+ 5*4096, s1h,s1l,s2h,s2l,b_s,cgp,tk0,tk1,wave,lane);
    tp_path<5,5,1,256,256,300>(wb,two+10*4096, s1h,s1l,s2h,s2l,b_s,cgp,tk0,tk1,wave,lane);
    store_hl(dh,dl, wave*SSTRIDE + lane,     tk0[0]*f192);
    store_hl(dh,dl, (wave+8)*SSTRIDE + lane, tk1[0]*f192);
  }
  { // out l1 @64 (fan 256): paths 1,4,6,11
    float tk0[3]={0,0,0}, tk1[3]={0,0,0};
    tp_path<1,3,3,  0, 64,  1>(wb,two+ 1*4096, s1h,s1l,s2h,s2l,b_s,cgp,tk0,tk1,wave,lane);
    tp_path<3,1,3, 64,  0, 10>(wb,two+ 4*4096, s1h,s1l,s2h,s2l,b_s,cgp,tk0,tk1,wave,lane);
    tp_path<3,3,3, 64, 64, 78>(wb,two+ 6*4096, s1h,s1l,s2h,s2l,b_s,cgp,tk0,tk1,wave,lane);
    tp_path<5,5,3,256,256,325>(wb,two+11*4096, s1h,s1l,s2h,s2l,b_s,cgp,tk0,tk1,wave,lane);
    #pragma unroll
    for (int k=0;k<3;k++){
      store_hl(dh,dl, wave*SSTRIDE + 64 + k*64 + lane,     tk0[k]*f256);
      store_hl(dh,dl, (wave+8)*SSTRIDE + 64 + k*64 + lane, tk1[k]*f256);
    }
  }
  { // out l2 @256 (fan 256): paths 2,8,9,13
    float tk0[5]={0,0,0,0,0}, tk1[5]={0,0,0,0,0};
    tp_path<1,5,5,  0,256, 19>(wb,two+ 2*4096, s1h,s1l,s2h,s2l,b_s,cgp,tk0,tk1,wave,lane);
    tp_path<5,1,5,256,  0, 44>(wb,two+ 8*4096, s1h,s1l,s2h,s2l,b_s,cgp,tk0,tk1,wave,lane);
    tp_path<5,3,5,256, 64,150>(wb,two+ 9*4096, s1h,s1l,s2h,s2l,b_s,cgp,tk0,tk1,wave,lane);
    tp_path<5,3,5,256,576,150>(wb,two+13*4096, s1h,s1l,s2h,s2l,b_s,cgp,tk0,tk1,wave,lane);
    #pragma unroll
    for (int k=0;k<5;k++){
      store_hl(dh,dl, wave*SSTRIDE + 256 + k*64 + lane,     tk0[k]*f256);
      store_hl(dh,dl, (wave+8)*SSTRIDE + 256 + k*64 + lane, tk1[k]*f256);
    }
  }
  { // out l1b @576 (fan 192): paths 3,7,12
    float tk0[3]={0,0,0}, tk1[3]={0,0,0};
    tp_path<1,3,3,  0,576,  1>(wb,two+ 3*4096, s1h,s1l,s2h,s2l,b_s,cgp,tk0,tk1,wave,lane);
    tp_path<3,3,3, 64, 64, 78>(wb,two+ 7*4096, s1h,s1l,s2h,s2l,b_s,cgp,tk0,tk1,wave,lane);
    tp_path<5,5,3,256,256,325>(wb,two+12*4096, s1h,s1l,s2h,s2l,b_s,cgp,tk0,tk1,wave,lane);
    #pragma unroll
    for (int k=0;k<3;k++){
      store_hl(dh,dl, wave*SSTRIDE + 576 + k*64 + lane,     tk0[k]*f192);
      store_hl(dh,dl, (wave+8)*SSTRIDE + 576 + k*64 + lane, tk1[k]*f192);
    }
  }
}

template<int D3>
__device__ __forceinline__ void wave_reduce_out(float* tk, float* s_out, int n, int lane, int iob){
  #pragma unroll
  for (int k=0;k<D3;k++){
    float v = tk[k];
    v += __shfl_down(v, 32, 64);
    v += __shfl_down(v, 16, 64);
    v += __shfl_down(v,  8, 64);
    v += __shfl_down(v,  4, 64);
    v += __shfl_down(v,  2, 64);
    v += __shfl_down(v,  1, 64);
    if (lane==0) s_out[n*6 + iob + k] = v;
  }
}

// ============================================================================
__global__ __launch_bounds__(NT) void deeprst_main(
    const float* __restrict__ x,
    const float* __restrict__ l1W0, const float* __restrict__ l1W1,
    const float* __restrict__ l1W2, const float* __restrict__ l1b0,
    const float* __restrict__ l2b0, const float* __restrict__ Lb0,
    const unsigned short* __restrict__ wb, const float* __restrict__ cgp,
    float* __restrict__ out)
{
  __shared__ unsigned short sth[3*BUF];   // 74496 B hi plane
  __shared__ unsigned short stl[3*BUF];   // 74496 B lo plane
  __shared__ float b_s[48*68];            // 13056 B

  const int tid  = threadIdx.x;
  const int lane = tid & 63;
  const int wave = tid >> 6;
  const int n0   = blockIdx.x * TS;
  const float rs8 = 0.3535533905932738f;

  // ---- lin1 (scalar fp32 -> hi/lo), h1 in buffers 0+1 of both planes ----
  for (int idx=tid; idx<TS*128; idx+=NT){
    int n=idx>>7, o=idx&127;
    const float* xp = x + (n0+n)*80;
    float acc=0.f;
    #pragma unroll
    for (int v=0;v<16;v++) acc += xp[v]*l1W0[v*128+o];
    store_hl(sth,stl, n*H1S + o, acc*0.25f + l1b0[o]);
  }
  for (int idx=tid; idx<TS*768; idx+=NT){
    int o=idx&255, i=(idx>>8)%3, n=idx/768;
    const float* xp = x + (n0+n)*80 + 16;
    float acc=0.f;
    #pragma unroll
    for (int v=0;v<8;v++) acc += xp[v*3+i]*l1W1[v*256+o];
    int du = (o<128)? (128 + i*128 + o) : (1152 + i*128 + o-128);
    store_hl(sth,stl, n*H1S + du, acc*rs8);
  }
  for (int idx=tid; idx<TS*640; idx+=NT){
    int o=idx&127, i=(idx>>7)%5, n=idx/640;
    const float* xp = x + (n0+n)*80 + 40;
    float acc=0.f;
    #pragma unroll
    for (int v=0;v<8;v++) acc += xp[v*5+i]*l1W2[v*128+o];
    store_hl(sth,stl, n*H1S + 512 + i*128 + o, acc*rs8);
  }
  __syncthreads();

  // ---- lin2 (MFMA hi/lo): h1 -> buffer 2 ----
  lin2_mfma(wb, l2b0, sth, stl, sth+2*BUF, stl+2*BUF, wave, lane);
  __syncthreads();

  // ---- 3 rounds: split -> tp_uvu -> linear ----
  int ih = 2, i0 = 0, i1 = 1;
  for (int r=0;r<3;r++){
    unsigned short *hh=sth+ih*BUF, *hl=stl+ih*BUF;
    unsigned short *ah=sth+i0*BUF, *al=stl+i0*BUF;
    unsigned short *bh=sth+i1*BUF, *bl=stl+i1*BUF;
    linL_mfma(wb, OFF_LW0+(3*r  )*4096, OFF_LW1+(3*r  )*16384, OFF_LW2+(3*r  )*4096,
              Lb0+(3*r  )*64, hh, hl, ah, al, wave, lane);
    linL_mfma(wb, OFF_LW0+(3*r+1)*4096, OFF_LW1+(3*r+1)*16384, OFF_LW2+(3*r+1)*4096,
              Lb0+(3*r+1)*64, hh, hl, bh, bl, wave, lane);
    // tp_chunk's leading barrier orders lin writes before TP reads
    tp_uvu_all(wb, OFF_TPW + r*14*4096, ah, al, bh, bl, hh, hl, b_s, cgp, wave, lane);
    __syncthreads();
    linL_mfma(wb, OFF_LW0+(3*r+2)*4096, OFF_LW1+(3*r+2)*16384, OFF_LW2+(3*r+2)*4096,
              Lb0+(3*r+2)*64, hh, hl, ah, al, wave, lane);
    __syncthreads();
    int nh=i0; i0=i1; i1=ih; ih=nh;
  }

  // ---- split4 + fully-connected TP ----
  unsigned short *hh=sth+ih*BUF, *hl=stl+ih*BUF;
  unsigned short *ah=sth+i0*BUF, *al=stl+i0*BUF;
  unsigned short *bh=sth+i1*BUF, *bl=stl+i1*BUF;
  linL_mfma(wb, OFF_LW0+ 9*4096, OFF_LW1+ 9*16384, OFF_LW2+ 9*4096, Lb0+ 9*64, hh, hl, ah, al, wave, lane);
  linL_mfma(wb, OFF_LW0+10*4096, OFF_LW1+10*16384, OFF_LW2+10*4096, Lb0+10*64, hh, hl, bh, bl, wave, lane);

  float* s_out = (float*)hh;   // h buffer dead after split4 linears (reads fenced
                               // by the first tp_chunk barrier below)
  { // out 0e (slot 0): fc paths 0..5
    float tk0[1]={0.f}, tk1[1]={0.f};
    tp_path<1,1,1,  0,  0,  0>(wb,OFF_TP4W+ 0*4096, ah,al,bh,bl,b_s,cgp,tk0,tk1,wave,lane);
    tp_path<3,3,1, 64, 64, 69>(wb,OFF_TP4W+ 1*4096, ah,al,bh,bl,b_s,cgp,tk0,tk1,wave,lane);
    tp_path<3,3,1, 64,576, 69>(wb,OFF_TP4W+ 2*4096, ah,al,bh,bl,b_s,cgp,tk0,tk1,wave,lane);
    tp_path<5,5,1,256,256,300>(wb,OFF_TP4W+ 3*4096, ah,al,bh,bl,b_s,cgp,tk0,tk1,wave,lane);
    tp_path<3,3,1,576, 64, 69>(wb,OFF_TP4W+ 4*4096, ah,al,bh,bl,b_s,cgp,tk0,tk1,wave,lane);
    tp_path<3,3,1,576,576, 69>(wb,OFF_TP4W+ 5*4096, ah,al,bh,bl,b_s,cgp,tk0,tk1,wave,lane);
    wave_reduce_out<1>(tk0, s_out, wave,   lane, 0);
    wave_reduce_out<1>(tk1, s_out, wave+8, lane, 0);
  }
  { // out 2e (slots 1..5): fc paths 6..16
    float tk0[5]={0,0,0,0,0}, tk1[5]={0,0,0,0,0};
    tp_path<1,5,5,  0,256, 19>(wb,OFF_TP4W+ 6*4096, ah,al,bh,bl,b_s,cgp,tk0,tk1,wave,lane);
    tp_path<3,3,5, 64, 64,105>(wb,OFF_TP4W+ 7*4096, ah,al,bh,bl,b_s,cgp,tk0,tk1,wave,lane);
    tp_path<3,5,5, 64,256,225>(wb,OFF_TP4W+ 8*4096, ah,al,bh,bl,b_s,cgp,tk0,tk1,wave,lane);
    tp_path<3,3,5, 64,576,105>(wb,OFF_TP4W+ 9*4096, ah,al,bh,bl,b_s,cgp,tk0,tk1,wave,lane);
    tp_path<5,1,5,256,  0, 44>(wb,OFF_TP4W+10*4096, ah,al,bh,bl,b_s,cgp,tk0,tk1,wave,lane);
    tp_path<5,3,5,256, 64,150>(wb,OFF_TP4W+11*4096, ah,al,bh,bl,b_s,cgp,tk0,tk1,wave,lane);
    tp_path<5,5,5,256,256,400>(wb,OFF_TP4W+12*4096, ah,al,bh,bl,b_s,cgp,tk0,tk1,wave,lane);
    tp_path<5,3,5,256,576,150>(wb,OFF_TP4W+13*4096, ah,al,bh,bl,b_s,cgp,tk0,tk1,wave,lane);
    tp_path<3,3,5,576, 64,105>(wb,OFF_TP4W+14*4096, ah,al,bh,bl,b_s,cgp,tk0,tk1,wave,lane);
    tp_path<3,5,5,576,256,225>(wb,OFF_TP4W+15*4096, ah,al,bh,bl,b_s,cgp,tk0,tk1,wave,lane);
    tp_path<3,3,5,576,576,105>(wb,OFF_TP4W+16*4096, ah,al,bh,bl,b_s,cgp,tk0,tk1,wave,lane);
    wave_reduce_out<5>(tk0, s_out, wave,   lane, 1);
    wave_reduce_out<5>(tk1, s_out, wave+8, lane, 1);
  }
  __syncthreads();

  if (tid < TS*6){
    int n=tid/6, k=tid%6;
    float sc = (k==0)? (1.0f/sqrtf(24576.0f)) : (1.0f/sqrtf(45056.0f));
    out[(n0+n)*6+k] = s_out[tid]*sc;
  }
}

// ============================================================================
extern "C" void kernel_launch(void* const* d_in, const int* in_sizes, int n_in,
                              void* d_out, int out_size, void* d_ws, size_t ws_size,
                              hipStream_t stream)
{
  (void)n_in; (void)out_size; (void)ws_size;
  const float* x    = (const float*)d_in[0];
  const float* l1W0 = (const float*)d_in[1];
  const float* l1W1 = (const float*)d_in[2];
  const float* l1W2 = (const float*)d_in[3];
  const float* l1b0 = (const float*)d_in[4];
  const float* l2W0 = (const float*)d_in[5];
  const float* l2W1 = (const float*)d_in[6];
  const float* l2W2 = (const float*)d_in[7];
  const float* l2b0 = (const float*)d_in[8];
  const float* LW0  = (const float*)d_in[9];
  const float* LW1  = (const float*)d_in[10];
  const float* LW2  = (const float*)d_in[11];
  const float* Lb0  = (const float*)d_in[12];
  const float* tpw  = (const float*)d_in[13];
  const float* tp4w = (const float*)d_in[14];

  float* cg = (float*)d_ws;                                    // 525 f32 @ ws+0
  unsigned short* wb = (unsigned short*)((char*)d_ws + 4096);  // hi + lo planes
  const int n = in_sizes[0]/80;

  cg_init_kernel<<<1, 576, 0, stream>>>(cg);
  prep_kernel<<<(W_TOT+255)/256, 256, 0, stream>>>(l2W0,l2W1,l2W2,LW0,LW1,LW2,tpw,tp4w,wb);
  deeprst_main<<<n/TS, NT, 0, stream>>>(x,l1W0,l1W1,l1W2,l1b0,l2b0,Lb0,wb,cg,(float*)d_out);
}